// Round 18
// baseline (105.974 us; speedup 1.0000x reference)
//
#include <hip/hip_runtime.h>
#include <math.h>
#include <stdint.h>

#define D_MODEL 1024
#define T_SEQ   2048
#define BATCH   2
#define NH      16
#define HD      64

typedef __attribute__((ext_vector_type(8))) short bf16x8;
typedef __attribute__((ext_vector_type(4))) float f32x4;

__device__ inline unsigned short f2bf(float f) {
  union { float f; unsigned int u; } v; v.f = f;
  unsigned int u = v.u;
  unsigned int r = u + 0x7fffu + ((u >> 16) & 1u);
  return (unsigned short)(r >> 16);
}
__device__ inline float bf2f(unsigned short s) {
  union { unsigned int u; float f; } v; v.u = ((unsigned int)s) << 16;
  return v.f;
}

// async global->LDS, 16B per lane, LDS dest = wave-uniform base + lane*16
#define GLDS16(g, l) __builtin_amdgcn_global_load_lds( \
  reinterpret_cast<const __attribute__((address_space(1))) void*>(reinterpret_cast<uintptr_t>(g)), \
  reinterpret_cast<__attribute__((address_space(3))) void*>(reinterpret_cast<uintptr_t>(l)), 16, 0, 0)

// P-quad store: rows r..r+3 at va+{0,144,288,432}; cvt_pk pairs (r0,r1),(r2,r3)
// (R7-verified form; va is a truncated flat addr — asm ds_write operand ONLY)
#define PSTORE(va_, p0_, p1_, p2_, p3_) do { \
  unsigned t0_, t1_; \
  asm volatile( \
    "v_cvt_pk_bf16_f32 %0, %3, %4\n\t" \
    "v_cvt_pk_bf16_f32 %1, %5, %6\n\t" \
    "ds_write_b16 %2, %0\n\t" \
    "ds_write_b16_d16_hi %2, %0 offset:144\n\t" \
    "ds_write_b16 %2, %1 offset:288\n\t" \
    "ds_write_b16_d16_hi %2, %1 offset:432" \
    : "=&v"(t0_), "=&v"(t1_) \
    : "v"(va_), "v"(p0_), "v"(p1_), "v"(p2_), "v"(p3_) \
    : "memory"); \
} while (0)

// ---------------- merged cast fp32 -> bf16: x + 4 weights, one dispatch ----------------
__global__ void cast5_kernel(const float* __restrict__ x,
                             const float* __restrict__ w0, const float* __restrict__ w1,
                             const float* __restrict__ w2, const float* __restrict__ w3,
                             unsigned short* __restrict__ xb,
                             unsigned short* __restrict__ d0, unsigned short* __restrict__ d1,
                             unsigned short* __restrict__ d2, unsigned short* __restrict__ d3) {
  int id = blockIdx.x * blockDim.x + threadIdx.x;   // 0 .. 2097151 float4s
  const float* s; unsigned short* dd; int r;
  if (id < (1 << 20)) { s = x; dd = xb; r = id; }
  else {
    int t = id - (1 << 20);
    int m = t >> 18; r = t & ((1 << 18) - 1);
    s  = (m == 0) ? w0 : (m == 1) ? w1 : (m == 2) ? w2 : w3;
    dd = (m == 0) ? d0 : (m == 1) ? d1 : (m == 2) ? d2 : d3;
  }
  float4 v = ((const float4*)s)[r];
  ushort4 o;
  o.x = f2bf(v.x); o.y = f2bf(v.y); o.z = f2bf(v.z); o.w = f2bf(v.w);
  ((ushort4*)dd)[r] = o;
}

// ---------------- GEMM: C[M,1024] = A[M,K] * B[1024,K]^T (bf16, fp32 acc) ----------------
// R12-verified staging/swizzle (BK=64, rule-#21 both-sides swizzle), now with
// template BM for occupancy: BM=64 doubles the grid -> 4-5 blocks/CU (grid
// was the 2-3/CU cap; LDS and VGPR allow more).
template<int BM, int BN, bool F32OUT, bool ROPE>
__global__ __launch_bounds__(256, 4)
void gemm_bt(const unsigned short* __restrict__ A,
             const unsigned short* __restrict__ B0, const unsigned short* __restrict__ B1,
             const unsigned short* __restrict__ B2,
             void* __restrict__ C0, void* __restrict__ C1, void* __restrict__ C2,
             const int* __restrict__ pos, int M, int K) {
  constexpr int NPM = 1024 / BN;
  constexpr int NWC = BN / 64;                     // wave columns
  constexpr int NWR = 4 / NWC;                     // wave rows
  constexpr int MI  = BM / (16 * NWR);             // M-frags per wave
  constexpr int NGA = BM / 8;                      // A granules (8 rows each)
  constexpr int NGB = BN / 8;                      // B granules
  __shared__ __align__(16) unsigned char As[NGA * 1024];
  __shared__ __align__(16) unsigned char Bs[NGB * 1024];

  const int tid = threadIdx.x, lane = tid & 63, wid = tid >> 6;
  const int wr = wid / NWC, wc = wid % NWC;
  const int bx = blockIdx.x;
  const int mat = bx / NPM;
  const int bn = (bx % NPM) * BN;
  const int bm = blockIdx.y * BM;
  const unsigned short* B = (mat == 0) ? B0 : (mat == 1) ? B1 : B2;
  void* C = (mat == 0) ? C0 : (mat == 1) ? C1 : C2;

  f32x4 acc[MI][4];
#pragma unroll
  for (int i = 0; i < MI; i++)
#pragma unroll
    for (int j = 0; j < 4; j++) acc[i][j] = (f32x4){0.f, 0.f, 0.f, 0.f};

  const int fr = lane & 15, fg = lane >> 4;
  const int srow = lane >> 3;                      // 0..7 within granule
  const int scg  = ((lane & 7) ^ (srow & 7)) * 8;  // pre-swizzled source col
  const int rx   = (fr & 7) << 4;                  // read-side XOR

  for (int kb = 0; kb < K; kb += 64) {
#pragma unroll
    for (int c = 0; c < NGA / 4; ++c) {
      int g = wid * (NGA / 4) + c;
      GLDS16(A + (size_t)(bm + g * 8 + srow) * K + kb + scg, As + g * 1024);
    }
#pragma unroll
    for (int c = 0; c < NGB / 4; ++c) {
      int g = wid * (NGB / 4) + c;
      GLDS16(B + (size_t)(bn + g * 8 + srow) * K + kb + scg, Bs + g * 1024);
    }
    __syncthreads();
#pragma unroll
    for (int h = 0; h < 2; ++h) {
      const int co = (h * 64 + fg * 16) ^ rx;      // swizzled col offset
      bf16x8 a[MI], bq[4];
#pragma unroll
      for (int mi = 0; mi < MI; mi++)
        a[mi] = *(const bf16x8*)(As + (wr * MI + mi) * 2048 + fr * 128 + co);
#pragma unroll
      for (int ni = 0; ni < 4; ni++)
        bq[ni] = *(const bf16x8*)(Bs + (wc * 4 + ni) * 2048 + fr * 128 + co);
#pragma unroll
      for (int mi = 0; mi < MI; mi++)
#pragma unroll
        for (int ni = 0; ni < 4; ni++)
          acc[mi][ni] = __builtin_amdgcn_mfma_f32_16x16x32_bf16(a[mi], bq[ni], acc[mi][ni], 0, 0, 0);
    }
    __syncthreads();
  }

  const int fc = lane & 15, fq = lane >> 4;

  if (ROPE && mat <= 1) {
    const float C1 = -0.4152410118609203f;     // -log2(10000)/32
    const float INV2PI = 0.15915494309189535f;
    const float scl = (mat == 0) ? 0.18033688011f : 1.0f;  // Q pre-scale (1/8)*log2e
    float inv[4];
#pragma unroll
    for (int ni = 0; ni < 4; ++ni) {
      int p = ((ni * 16 + fc) >> 1) & 31;      // pair index within head
      inv[ni] = __builtin_amdgcn_exp2f(C1 * (float)p) * INV2PI;
    }
    const float sgn = (fc & 1) ? 1.0f : -1.0f;
#pragma unroll
    for (int mi = 0; mi < MI; ++mi)
#pragma unroll
      for (int r = 0; r < 4; ++r) {
        int row = bm + wr * (16 * MI) + mi * 16 + fq * 4 + r;
        float posf = (float)pos[row];
#pragma unroll
        for (int ni = 0; ni < 4; ++ni) {
          float v = acc[mi][ni][r];
          float partner = __shfl_xor(v, 1);
          float rev = posf * inv[ni];
          rev = __builtin_amdgcn_fractf(rev);  // v_sin/v_cos take revolutions
          float sn, cs;
          asm("v_sin_f32 %0, %1" : "=v"(sn) : "v"(rev));
          asm("v_cos_f32 %0, %1" : "=v"(cs) : "v"(rev));
          acc[mi][ni][r] = (v * cs + partner * sn * sgn) * scl;
        }
      }
  }

#pragma unroll
  for (int mi = 0; mi < MI; mi++)
#pragma unroll
    for (int ni = 0; ni < 4; ni++) {
      int col = bn + wc * 64 + ni * 16 + fc;
#pragma unroll
      for (int r = 0; r < 4; r++) {
        int row = bm + wr * (16 * MI) + mi * 16 + fq * 4 + r;
        if (F32OUT) ((float*)C)[(size_t)row * 1024 + col] = acc[mi][ni][r];
        else ((unsigned short*)C)[(size_t)row * 1024 + col] = f2bf(acc[mi][ni][r]);
      }
    }
}

// ---------------- Flash attention, causal, bf16 MFMA (R17-verified, 47.3 us) ----------------
// Unpaired single-phase blocks (one 64-row q-tile), grid 1024 with balanced-
// quadruple XCD-grouped decode, 3 blocks/CU. Inner unit/Ps/PSTORE = R7/R12.
__global__ __launch_bounds__(256, 3)
void attn_kernel(const unsigned short* __restrict__ Q, const unsigned short* __restrict__ K,
                 const unsigned short* __restrict__ V, unsigned short* __restrict__ O) {
  __shared__ __align__(16) unsigned char KsRaw[2][8192];   // [buf][idx=nt*2+half][lane][16B]
  __shared__ __align__(16) unsigned char VtRaw[2][8192];   // [buf][d][128B swz row]
  __shared__ __align__(16) unsigned char PsRaw[4][2304];   // [wave][row*144 swizzled]

  const int lin = (int)blockIdx.x;           // 0..1023
  const int xcd = lin & 7;
  const int cu  = (lin >> 3) & 31;
  const int rnd = lin >> 8;                  // 0..3 (big q-tiles first)
  const int k4  = cu >> 2;                   // 0..7
  const int bh  = xcd | ((cu & 3) << 3);     // 4 heads per XCD
  const int qt  = (rnd == 0) ? 31 - k4 : (rnd == 1) ? 16 + k4 : (rnd == 2) ? 15 - k4 : k4;
  const int b  = bh >> 4, h = bh & 15;
  const int tid = threadIdx.x, lane = tid & 63, wid = tid >> 6;
  const int fr = lane & 15, fg = lane >> 4;

  const size_t base = ((size_t)b * T_SEQ) * D_MODEL + h * HD;
  const unsigned short* Qb = Q + base;
  const unsigned short* Kb = K + base;
  const unsigned short* Vb = V + base;

  const int ntk = qt + 1;                    // 64-kv tiles

  // Q frags (pre-scaled in GEMM epilogue)
  bf16x8 qf0, qf1;
  {
    const unsigned short* qp = Qb + (size_t)(qt * 64 + wid * 16 + fr) * D_MODEL + fg * 8;
    qf0 = *(const bf16x8*)qp;  qf1 = *(const bf16x8*)(qp + 32);
  }

  // V staging: thread -> kv-pair sg (0..31), d-range sd0..sd0+7
  const int sg  = tid >> 3;
  const int sd0 = (tid & 7) * 8;
  const int sx  = tid & 7;

#define STAGE_K(kvbase, buf) do { \
    _Pragma("unroll") \
    for (int c_ = 0; c_ < 2; ++c_) { \
      int idx_ = wid * 2 + c_; \
      int nt_ = idx_ >> 1, hf_ = idx_ & 1; \
      GLDS16(Kb + (size_t)((kvbase) + nt_ * 16 + fr) * D_MODEL + hf_ * 32 + fg * 8, \
             &KsRaw[buf][idx_ * 1024]); \
    } \
  } while (0)

#define STAGE_V_WRITE(ra_, rb_, bufp_) do { \
    _Pragma("unroll") \
    for (int j_ = 0; j_ < 8; ++j_) { \
      unsigned pk_ = (unsigned)(unsigned short)(ra_)[j_] | ((unsigned)(unsigned short)(rb_)[j_] << 16); \
      *(unsigned*)((bufp_) + (sd0 + j_) * 128 + ((sg * 4) ^ ((j_ ^ sx) << 4))) = pk_; \
    } \
  } while (0)

  // prologue: stage K tile 0 (async) + V tile 0 into buf 0
  STAGE_K(0, 0);
  {
    bf16x8 ra = *(const bf16x8*)(Vb + (size_t)(2 * sg    ) * D_MODEL + sd0);
    bf16x8 rb = *(const bf16x8*)(Vb + (size_t)(2 * sg + 1) * D_MODEL + sd0);
    STAGE_V_WRITE(ra, rb, &VtRaw[0][0]);
  }

  // precomputed P-store addresses: PsRaw[wid] + fg*576 + ((nt*32+fr*2)^(fg<<5))
  unsigned pva[4];
  {
    unsigned psb = (unsigned)(uintptr_t)(void*)&PsRaw[wid][0];
#pragma unroll
    for (int nt = 0; nt < 4; ++nt)
      pva[nt] = psb + fg * 576 + (unsigned)((nt * 32 + fr * 2) ^ (fg << 5));
  }

  float m_run[4], l_part[4];
  f32x4 acc[4];
#pragma unroll
  for (int r = 0; r < 4; ++r) { m_run[r] = -INFINITY; l_part[r] = 0.f; }
#pragma unroll
  for (int d = 0; d < 4; ++d) acc[d] = (f32x4){0.f, 0.f, 0.f, 0.f};

  // one kv-unit: compute on buf `par`, prefetch kvn into buf par^1 (if hn)
#define UNIT(kt_, par_, hn_, kvn_) do { \
    __syncthreads(); \
    bf16x8 nva, nvb; \
    if (hn_) { \
      STAGE_K(kvn_, (par_) ^ 1); \
      nva = *(const bf16x8*)(Vb + (size_t)((kvn_) + 2 * sg    ) * D_MODEL + sd0); \
      nvb = *(const bf16x8*)(Vb + (size_t)((kvn_) + 2 * sg + 1) * D_MODEL + sd0); \
    } \
    const unsigned char* kbuf = &KsRaw[par_][0]; \
    f32x4 st[4]; \
    __builtin_amdgcn_s_setprio(1); \
    _Pragma("unroll") \
    for (int nt = 0; nt < 4; ++nt) { \
      bf16x8 kf0 = *(const bf16x8*)(kbuf + (nt * 2    ) * 1024 + lane * 16); \
      bf16x8 kf1 = *(const bf16x8*)(kbuf + (nt * 2 + 1) * 1024 + lane * 16); \
      f32x4 sa = (f32x4){0.f, 0.f, 0.f, 0.f}; \
      sa = __builtin_amdgcn_mfma_f32_16x16x32_bf16(qf0, kf0, sa, 0, 0, 0); \
      sa = __builtin_amdgcn_mfma_f32_16x16x32_bf16(qf1, kf1, sa, 0, 0, 0); \
      st[nt] = sa; \
    } \
    __builtin_amdgcn_s_setprio(0); \
    float p[4][4]; \
    _Pragma("unroll") \
    for (int nt = 0; nt < 4; ++nt) \
      _Pragma("unroll") \
      for (int r = 0; r < 4; ++r) p[nt][r] = st[nt][r]; \
    if ((kt_) == qt) {   /* diagonal tile: mask cols > row */ \
      _Pragma("unroll") \
      for (int nt = 0; nt < 4; ++nt) { \
        _Pragma("unroll") \
        for (int r = 0; r < 4; ++r) \
          if (nt * 16 + fr > wid * 16 + fg * 4 + r) p[nt][r] = -INFINITY; \
      } \
    } \
    float lmax[4]; \
    bool ok = true; \
    _Pragma("unroll") \
    for (int r = 0; r < 4; ++r) { \
      lmax[r] = fmaxf(fmaxf(p[0][r], p[1][r]), fmaxf(p[2][r], p[3][r])); \
      ok = ok && (lmax[r] <= m_run[r] + 8.0f); \
    } \
    if (!__all(ok)) { \
      _Pragma("unroll") \
      for (int r = 0; r < 4; ++r) { \
        float tm = lmax[r]; \
        tm = fmaxf(tm, __shfl_xor(tm, 1)); \
        tm = fmaxf(tm, __shfl_xor(tm, 2)); \
        tm = fmaxf(tm, __shfl_xor(tm, 4)); \
        tm = fmaxf(tm, __shfl_xor(tm, 8)); \
        float mn = fmaxf(m_run[r], tm); \
        float sc = __builtin_amdgcn_exp2f(m_run[r] - mn); \
        m_run[r] = mn; \
        l_part[r] *= sc; \
        _Pragma("unroll") \
        for (int d = 0; d < 4; ++d) acc[d][r] *= sc; \
      } \
    } \
    _Pragma("unroll") \
    for (int nt = 0; nt < 4; ++nt) { \
      float pv0 = __builtin_amdgcn_exp2f(p[nt][0] - m_run[0]); \
      float pv1 = __builtin_amdgcn_exp2f(p[nt][1] - m_run[1]); \
      float pv2 = __builtin_amdgcn_exp2f(p[nt][2] - m_run[2]); \
      float pv3 = __builtin_amdgcn_exp2f(p[nt][3] - m_run[3]); \
      l_part[0] += pv0; l_part[1] += pv1; l_part[2] += pv2; l_part[3] += pv3; \
      PSTORE(pva[nt], pv0, pv1, pv2, pv3); \
    } \
    asm volatile("s_waitcnt lgkmcnt(0)" ::: "memory"); \
    __builtin_amdgcn_sched_barrier(0); \
    bf16x8 pa0 = *(const bf16x8*)(&PsRaw[wid][0] + fr * 144 + ((     fg * 16) ^ ((fr >> 2) << 5))); \
    bf16x8 pa1 = *(const bf16x8*)(&PsRaw[wid][0] + fr * 144 + ((64 + fg * 16) ^ ((fr >> 2) << 5))); \
    const unsigned char* vbuf = &VtRaw[par_][0]; \
    __builtin_amdgcn_s_setprio(1); \
    _Pragma("unroll") \
    for (int dblk = 0; dblk < 4; ++dblk) { \
      int xr = ((fr & 7) ^ ((dblk * 2 + (fr >> 3)) & 7)) << 4; \
      const unsigned char* vp = vbuf + (dblk * 16 + fr) * 128; \
      bf16x8 b0 = *(const bf16x8*)(vp + ((fg * 16) ^ xr)); \
      bf16x8 b1 = *(const bf16x8*)(vp + ((64 + fg * 16) ^ xr)); \
      acc[dblk] = __builtin_amdgcn_mfma_f32_16x16x32_bf16(pa0, b0, acc[dblk], 0, 0, 0); \
      acc[dblk] = __builtin_amdgcn_mfma_f32_16x16x32_bf16(pa1, b1, acc[dblk], 0, 0, 0); \
    } \
    __builtin_amdgcn_s_setprio(0); \
    if (hn_) STAGE_V_WRITE(nva, nvb, &VtRaw[(par_) ^ 1][0]); \
  } while (0)

  int par = 0;
  for (int kt = 0; kt < ntk; ++kt) {
    bool hn = (kt + 1 < ntk);
    UNIT(kt, par, hn, (kt + 1) * 64);
    par ^= 1;
  }

  // epilogue
#pragma unroll
  for (int r = 0; r < 4; ++r) {
    float l = l_part[r];
    l += __shfl_xor(l, 1); l += __shfl_xor(l, 2);
    l += __shfl_xor(l, 4); l += __shfl_xor(l, 8);
    float rl = __builtin_amdgcn_rcpf(l);
    int row = qt * 64 + wid * 16 + fg * 4 + r;
    unsigned short* orow = O + ((size_t)b * T_SEQ + row) * D_MODEL + h * HD;
#pragma unroll
    for (int d = 0; d < 4; ++d) orow[d * 16 + fr] = f2bf(acc[d][r] * rl);
  }
#undef UNIT
#undef STAGE_K
#undef STAGE_V_WRITE
}

// ---------------- launch ----------------
extern "C" void kernel_launch(void* const* d_in, const int* in_sizes, int n_in,
                              void* d_out, int out_size, void* d_ws, size_t ws_size,
                              hipStream_t stream) {
  const float* x   = (const float*)d_in[0];
  const int*   pos = (const int*)d_in[1];
  const float* Wq  = (const float*)d_in[2];
  const float* Wk  = (const float*)d_in[3];
  const float* Wv  = (const float*)d_in[4];
  const float* Wo  = (const float*)d_in[5];

  const size_t M  = (size_t)BATCH * T_SEQ;   // 4096
  const size_t DD = (size_t)D_MODEL * D_MODEL;

  char* ws = (char*)d_ws;
  unsigned short* xb  = (unsigned short*)ws; ws += M * D_MODEL * 2;
  unsigned short* Wqb = (unsigned short*)ws; ws += DD * 2;
  unsigned short* Wkb = (unsigned short*)ws; ws += DD * 2;
  unsigned short* Wvb = (unsigned short*)ws; ws += DD * 2;
  unsigned short* Wob = (unsigned short*)ws; ws += DD * 2;
  unsigned short* Qp  = (unsigned short*)ws; ws += M * D_MODEL * 2;
  unsigned short* Kp  = (unsigned short*)ws; ws += M * D_MODEL * 2;
  unsigned short* Vp  = (unsigned short*)ws; ws += M * D_MODEL * 2;
  unsigned short* Ob  = (unsigned short*)ws; ws += M * D_MODEL * 2;

  // merged casts: x + 4 weights, one dispatch (2^21 float4s)
  cast5_kernel<<<8192, 256, 0, stream>>>(x, Wq, Wk, Wv, Wo, xb, Wqb, Wkb, Wvb, Wob);

  // fused QKV projection with RoPE in epilogue: BM=64, BN=128 -> 1536 blocks
  gemm_bt<64, 128, false, true><<<dim3(24, (unsigned)(M / 64)), 256, 0, stream>>>(
      xb, Wqb, Wkb, Wvb, Qp, Kp, Vp, pos, (int)M, D_MODEL);

  // attention: unpaired 1024 blocks, balanced quadruples (big first), XCD-grouped
  attn_kernel<<<dim3(1024), 256, 0, stream>>>(Qp, Kp, Vp, Ob);

  // output projection (fp32 out): BM=64, BN=64 -> 1024 blocks = 4/CU
  gemm_bt<64, 64, true, false><<<dim3(16, (unsigned)(M / 64)), 256, 0, stream>>>(
      Ob, Wob, Wob, Wob, d_out, d_out, d_out, nullptr, (int)M, D_MODEL);
}

// Round 19
// 99.410 us; speedup vs baseline: 1.0660x; 1.0660x over previous
//
#include <hip/hip_runtime.h>
#include <math.h>
#include <stdint.h>

#define D_MODEL 1024
#define T_SEQ   2048
#define BATCH   2
#define NH      16
#define HD      64

typedef __attribute__((ext_vector_type(8))) short bf16x8;
typedef __attribute__((ext_vector_type(4))) float f32x4;

__device__ inline unsigned short f2bf(float f) {
  union { float f; unsigned int u; } v; v.f = f;
  unsigned int u = v.u;
  unsigned int r = u + 0x7fffu + ((u >> 16) & 1u);
  return (unsigned short)(r >> 16);
}
__device__ inline float bf2f(unsigned short s) {
  union { unsigned int u; float f; } v; v.u = ((unsigned int)s) << 16;
  return v.f;
}

// async global->LDS, 16B per lane, LDS dest = wave-uniform base + lane*16
#define GLDS16(g, l) __builtin_amdgcn_global_load_lds( \
  reinterpret_cast<const __attribute__((address_space(1))) void*>(reinterpret_cast<uintptr_t>(g)), \
  reinterpret_cast<__attribute__((address_space(3))) void*>(reinterpret_cast<uintptr_t>(l)), 16, 0, 0)

// P-quad store: rows r..r+3 at va+{0,144,288,432}; cvt_pk pairs (r0,r1),(r2,r3)
// (va is a truncated flat addr — asm ds_write operand ONLY, never deref)
#define PSTORE(va_, p0_, p1_, p2_, p3_) do { \
  unsigned t0_, t1_; \
  asm volatile( \
    "v_cvt_pk_bf16_f32 %0, %3, %4\n\t" \
    "v_cvt_pk_bf16_f32 %1, %5, %6\n\t" \
    "ds_write_b16 %2, %0\n\t" \
    "ds_write_b16_d16_hi %2, %0 offset:144\n\t" \
    "ds_write_b16 %2, %1 offset:288\n\t" \
    "ds_write_b16_d16_hi %2, %1 offset:432" \
    : "=&v"(t0_), "=&v"(t1_) \
    : "v"(va_), "v"(p0_), "v"(p1_), "v"(p2_), "v"(p3_) \
    : "memory"); \
} while (0)

// ---------------- merged cast fp32 -> bf16: x + 4 weights, one dispatch ----------------
__global__ void cast5_kernel(const float* __restrict__ x,
                             const float* __restrict__ w0, const float* __restrict__ w1,
                             const float* __restrict__ w2, const float* __restrict__ w3,
                             unsigned short* __restrict__ xb,
                             unsigned short* __restrict__ d0, unsigned short* __restrict__ d1,
                             unsigned short* __restrict__ d2, unsigned short* __restrict__ d3) {
  int id = blockIdx.x * blockDim.x + threadIdx.x;   // 0 .. 2097151 float4s
  const float* s; unsigned short* dd; int r;
  if (id < (1 << 20)) { s = x; dd = xb; r = id; }
  else {
    int t = id - (1 << 20);
    int m = t >> 18; r = t & ((1 << 18) - 1);
    s  = (m == 0) ? w0 : (m == 1) ? w1 : (m == 2) ? w2 : w3;
    dd = (m == 0) ? d0 : (m == 1) ? d1 : (m == 2) ? d2 : d3;
  }
  float4 v = ((const float4*)s)[r];
  ushort4 o;
  o.x = f2bf(v.x); o.y = f2bf(v.y); o.z = f2bf(v.z); o.w = f2bf(v.w);
  ((ushort4*)dd)[r] = o;
}

// ---------------- GEMM: C[M,1024] = A[M,K] * B[1024,K]^T (bf16, fp32 acc) ----------------
// R12-verified: BK=64 + rule-#21 both-sides swizzle (LDS dest linear for
// global_load_lds; SOURCE colgroup XOR-permuted within each 128B row; reads
// XOR (fr&7)<<4 -> 2 lanes/bank). BM=128 (R18's BM=64 regressed: B-panel
// refetch x2 + per-block overhead outweigh occupancy).
template<int BN, bool F32OUT, bool ROPE>
__global__ __launch_bounds__(256, 3)
void gemm_bt(const unsigned short* __restrict__ A,
             const unsigned short* __restrict__ B0, const unsigned short* __restrict__ B1,
             const unsigned short* __restrict__ B2,
             void* __restrict__ C0, void* __restrict__ C1, void* __restrict__ C2,
             const int* __restrict__ pos, int M, int K) {
  constexpr int NPM = 1024 / BN;
  constexpr int NWC = BN / 64;
  constexpr int MI  = 2 * NWC;
  constexpr int NGB = BN / 8;                      // B granules (8 rows each)
  __shared__ __align__(16) unsigned char As[16 * 1024];   // 128 rows x 64 cols bf16
  __shared__ __align__(16) unsigned char Bs[NGB * 1024];  // BN rows x 64 cols bf16

  const int tid = threadIdx.x, lane = tid & 63, wid = tid >> 6;
  const int wr = wid / NWC, wc = wid % NWC;
  const int bx = blockIdx.x;
  const int mat = bx / NPM;
  const int bn = (bx % NPM) * BN;
  const int bm = blockIdx.y * 128;
  const unsigned short* B = (mat == 0) ? B0 : (mat == 1) ? B1 : B2;
  void* C = (mat == 0) ? C0 : (mat == 1) ? C1 : C2;

  f32x4 acc[MI][4];
#pragma unroll
  for (int i = 0; i < MI; i++)
#pragma unroll
    for (int j = 0; j < 4; j++) acc[i][j] = (f32x4){0.f, 0.f, 0.f, 0.f};

  const int fr = lane & 15, fg = lane >> 4;
  const int srow = lane >> 3;                      // 0..7 within granule
  const int scg  = ((lane & 7) ^ (srow & 7)) * 8;  // pre-swizzled source col
  const int rx   = (fr & 7) << 4;                  // read-side XOR

  for (int kb = 0; kb < K; kb += 64) {
#pragma unroll
    for (int c = 0; c < 4; ++c) {
      int g = wid * 4 + c;
      GLDS16(A + (size_t)(bm + g * 8 + srow) * K + kb + scg, As + g * 1024);
    }
#pragma unroll
    for (int c = 0; c < NGB / 4; ++c) {
      int g = wid * (NGB / 4) + c;
      GLDS16(B + (size_t)(bn + g * 8 + srow) * K + kb + scg, Bs + g * 1024);
    }
    __syncthreads();
#pragma unroll
    for (int h = 0; h < 2; ++h) {
      const int co = (h * 64 + fg * 16) ^ rx;      // swizzled col offset
      bf16x8 a[MI], bq[4];
#pragma unroll
      for (int mi = 0; mi < MI; mi++)
        a[mi] = *(const bf16x8*)(As + (wr * MI + mi) * 2048 + fr * 128 + co);
#pragma unroll
      for (int ni = 0; ni < 4; ni++)
        bq[ni] = *(const bf16x8*)(Bs + (wc * 4 + ni) * 2048 + fr * 128 + co);
#pragma unroll
      for (int mi = 0; mi < MI; mi++)
#pragma unroll
        for (int ni = 0; ni < 4; ni++)
          acc[mi][ni] = __builtin_amdgcn_mfma_f32_16x16x32_bf16(a[mi], bq[ni], acc[mi][ni], 0, 0, 0);
    }
    __syncthreads();
  }

  const int fc = lane & 15, fq = lane >> 4;

  if (ROPE && mat <= 1) {
    const float C1 = -0.4152410118609203f;     // -log2(10000)/32
    const float INV2PI = 0.15915494309189535f;
    const float scl = (mat == 0) ? 0.18033688011f : 1.0f;  // Q pre-scale (1/8)*log2e
    float inv[4];
#pragma unroll
    for (int ni = 0; ni < 4; ++ni) {
      int p = ((ni * 16 + fc) >> 1) & 31;      // pair index within head
      inv[ni] = __builtin_amdgcn_exp2f(C1 * (float)p) * INV2PI;
    }
    const float sgn = (fc & 1) ? 1.0f : -1.0f;
#pragma unroll
    for (int mi = 0; mi < MI; ++mi)
#pragma unroll
      for (int r = 0; r < 4; ++r) {
        int row = bm + wr * (16 * MI) + mi * 16 + fq * 4 + r;
        float posf = (float)pos[row];
#pragma unroll
        for (int ni = 0; ni < 4; ++ni) {
          float v = acc[mi][ni][r];
          float partner = __shfl_xor(v, 1);
          float rev = posf * inv[ni];
          rev = __builtin_amdgcn_fractf(rev);  // v_sin/v_cos take revolutions
          float sn, cs;
          asm("v_sin_f32 %0, %1" : "=v"(sn) : "v"(rev));
          asm("v_cos_f32 %0, %1" : "=v"(cs) : "v"(rev));
          acc[mi][ni][r] = (v * cs + partner * sn * sgn) * scl;
        }
      }
  }

#pragma unroll
  for (int mi = 0; mi < MI; mi++)
#pragma unroll
    for (int ni = 0; ni < 4; ni++) {
      int col = bn + wc * 64 + ni * 16 + fc;
#pragma unroll
      for (int r = 0; r < 4; r++) {
        int row = bm + wr * (16 * MI) + mi * 16 + fq * 4 + r;
        if (F32OUT) ((float*)C)[(size_t)row * 1024 + col] = acc[mi][ni][r];
        else ((unsigned short*)C)[(size_t)row * 1024 + col] = f2bf(acc[mi][ni][r]);
      }
    }
}

// ---------------- Flash attention, causal, bf16 MFMA (R17-verified, 47.3 us) ----------------
// Unpaired single-phase blocks (one 64-row q-tile), grid 1024 with balanced-
// quadruple XCD-grouped decode (big tiles first), 3 blocks/CU. Inner unit,
// Ps layout, PSTORE, pa reads = R7/R12 verbatim.
__global__ __launch_bounds__(256, 3)
void attn_kernel(const unsigned short* __restrict__ Q, const unsigned short* __restrict__ K,
                 const unsigned short* __restrict__ V, unsigned short* __restrict__ O) {
  __shared__ __align__(16) unsigned char KsRaw[2][8192];   // [buf][idx=nt*2+half][lane][16B]
  __shared__ __align__(16) unsigned char VtRaw[2][8192];   // [buf][d][128B swz row]
  __shared__ __align__(16) unsigned char PsRaw[4][2304];   // [wave][row*144 swizzled]

  const int lin = (int)blockIdx.x;           // 0..1023
  const int xcd = lin & 7;
  const int cu  = (lin >> 3) & 31;
  const int rnd = lin >> 8;                  // 0..3 (big q-tiles first)
  const int k4  = cu >> 2;                   // 0..7
  const int bh  = xcd | ((cu & 3) << 3);     // 4 heads per XCD
  const int qt  = (rnd == 0) ? 31 - k4 : (rnd == 1) ? 16 + k4 : (rnd == 2) ? 15 - k4 : k4;
  const int b  = bh >> 4, h = bh & 15;
  const int tid = threadIdx.x, lane = tid & 63, wid = tid >> 6;
  const int fr = lane & 15, fg = lane >> 4;

  const size_t base = ((size_t)b * T_SEQ) * D_MODEL + h * HD;
  const unsigned short* Qb = Q + base;
  const unsigned short* Kb = K + base;
  const unsigned short* Vb = V + base;

  const int ntk = qt + 1;                    // 64-kv tiles

  // Q frags (pre-scaled in GEMM epilogue)
  bf16x8 qf0, qf1;
  {
    const unsigned short* qp = Qb + (size_t)(qt * 64 + wid * 16 + fr) * D_MODEL + fg * 8;
    qf0 = *(const bf16x8*)qp;  qf1 = *(const bf16x8*)(qp + 32);
  }

  // V staging: thread -> kv-pair sg (0..31), d-range sd0..sd0+7
  const int sg  = tid >> 3;
  const int sd0 = (tid & 7) * 8;
  const int sx  = tid & 7;

#define STAGE_K(kvbase, buf) do { \
    _Pragma("unroll") \
    for (int c_ = 0; c_ < 2; ++c_) { \
      int idx_ = wid * 2 + c_; \
      int nt_ = idx_ >> 1, hf_ = idx_ & 1; \
      GLDS16(Kb + (size_t)((kvbase) + nt_ * 16 + fr) * D_MODEL + hf_ * 32 + fg * 8, \
             &KsRaw[buf][idx_ * 1024]); \
    } \
  } while (0)

#define STAGE_V_WRITE(ra_, rb_, bufp_) do { \
    _Pragma("unroll") \
    for (int j_ = 0; j_ < 8; ++j_) { \
      unsigned pk_ = (unsigned)(unsigned short)(ra_)[j_] | ((unsigned)(unsigned short)(rb_)[j_] << 16); \
      *(unsigned*)((bufp_) + (sd0 + j_) * 128 + ((sg * 4) ^ ((j_ ^ sx) << 4))) = pk_; \
    } \
  } while (0)

  // prologue: stage K tile 0 (async) + V tile 0 into buf 0
  STAGE_K(0, 0);
  {
    bf16x8 ra = *(const bf16x8*)(Vb + (size_t)(2 * sg    ) * D_MODEL + sd0);
    bf16x8 rb = *(const bf16x8*)(Vb + (size_t)(2 * sg + 1) * D_MODEL + sd0);
    STAGE_V_WRITE(ra, rb, &VtRaw[0][0]);
  }

  // precomputed P-store addresses: PsRaw[wid] + fg*576 + ((nt*32+fr*2)^(fg<<5))
  unsigned pva[4];
  {
    unsigned psb = (unsigned)(uintptr_t)(void*)&PsRaw[wid][0];
#pragma unroll
    for (int nt = 0; nt < 4; ++nt)
      pva[nt] = psb + fg * 576 + (unsigned)((nt * 32 + fr * 2) ^ (fg << 5));
  }

  float m_run[4], l_part[4];
  f32x4 acc[4];
#pragma unroll
  for (int r = 0; r < 4; ++r) { m_run[r] = -INFINITY; l_part[r] = 0.f; }
#pragma unroll
  for (int d = 0; d < 4; ++d) acc[d] = (f32x4){0.f, 0.f, 0.f, 0.f};

  // one kv-unit: compute on buf `par`, prefetch kvn into buf par^1 (if hn)
#define UNIT(kt_, par_, hn_, kvn_) do { \
    __syncthreads(); \
    bf16x8 nva, nvb; \
    if (hn_) { \
      STAGE_K(kvn_, (par_) ^ 1); \
      nva = *(const bf16x8*)(Vb + (size_t)((kvn_) + 2 * sg    ) * D_MODEL + sd0); \
      nvb = *(const bf16x8*)(Vb + (size_t)((kvn_) + 2 * sg + 1) * D_MODEL + sd0); \
    } \
    const unsigned char* kbuf = &KsRaw[par_][0]; \
    f32x4 st[4]; \
    __builtin_amdgcn_s_setprio(1); \
    _Pragma("unroll") \
    for (int nt = 0; nt < 4; ++nt) { \
      bf16x8 kf0 = *(const bf16x8*)(kbuf + (nt * 2    ) * 1024 + lane * 16); \
      bf16x8 kf1 = *(const bf16x8*)(kbuf + (nt * 2 + 1) * 1024 + lane * 16); \
      f32x4 sa = (f32x4){0.f, 0.f, 0.f, 0.f}; \
      sa = __builtin_amdgcn_mfma_f32_16x16x32_bf16(qf0, kf0, sa, 0, 0, 0); \
      sa = __builtin_amdgcn_mfma_f32_16x16x32_bf16(qf1, kf1, sa, 0, 0, 0); \
      st[nt] = sa; \
    } \
    __builtin_amdgcn_s_setprio(0); \
    float p[4][4]; \
    _Pragma("unroll") \
    for (int nt = 0; nt < 4; ++nt) \
      _Pragma("unroll") \
      for (int r = 0; r < 4; ++r) p[nt][r] = st[nt][r]; \
    if ((kt_) == qt) {   /* diagonal tile: mask cols > row */ \
      _Pragma("unroll") \
      for (int nt = 0; nt < 4; ++nt) { \
        _Pragma("unroll") \
        for (int r = 0; r < 4; ++r) \
          if (nt * 16 + fr > wid * 16 + fg * 4 + r) p[nt][r] = -INFINITY; \
      } \
    } \
    float lmax[4]; \
    bool ok = true; \
    _Pragma("unroll") \
    for (int r = 0; r < 4; ++r) { \
      lmax[r] = fmaxf(fmaxf(p[0][r], p[1][r]), fmaxf(p[2][r], p[3][r])); \
      ok = ok && (lmax[r] <= m_run[r] + 8.0f); \
    } \
    if (!__all(ok)) { \
      _Pragma("unroll") \
      for (int r = 0; r < 4; ++r) { \
        float tm = lmax[r]; \
        tm = fmaxf(tm, __shfl_xor(tm, 1)); \
        tm = fmaxf(tm, __shfl_xor(tm, 2)); \
        tm = fmaxf(tm, __shfl_xor(tm, 4)); \
        tm = fmaxf(tm, __shfl_xor(tm, 8)); \
        float mn = fmaxf(m_run[r], tm); \
        float sc = __builtin_amdgcn_exp2f(m_run[r] - mn); \
        m_run[r] = mn; \
        l_part[r] *= sc; \
        _Pragma("unroll") \
        for (int d = 0; d < 4; ++d) acc[d][r] *= sc; \
      } \
    } \
    _Pragma("unroll") \
    for (int nt = 0; nt < 4; ++nt) { \
      float pv0 = __builtin_amdgcn_exp2f(p[nt][0] - m_run[0]); \
      float pv1 = __builtin_amdgcn_exp2f(p[nt][1] - m_run[1]); \
      float pv2 = __builtin_amdgcn_exp2f(p[nt][2] - m_run[2]); \
      float pv3 = __builtin_amdgcn_exp2f(p[nt][3] - m_run[3]); \
      l_part[0] += pv0; l_part[1] += pv1; l_part[2] += pv2; l_part[3] += pv3; \
      PSTORE(pva[nt], pv0, pv1, pv2, pv3); \
    } \
    asm volatile("s_waitcnt lgkmcnt(0)" ::: "memory"); \
    __builtin_amdgcn_sched_barrier(0); \
    bf16x8 pa0 = *(const bf16x8*)(&PsRaw[wid][0] + fr * 144 + ((     fg * 16) ^ ((fr >> 2) << 5))); \
    bf16x8 pa1 = *(const bf16x8*)(&PsRaw[wid][0] + fr * 144 + ((64 + fg * 16) ^ ((fr >> 2) << 5))); \
    const unsigned char* vbuf = &VtRaw[par_][0]; \
    __builtin_amdgcn_s_setprio(1); \
    _Pragma("unroll") \
    for (int dblk = 0; dblk < 4; ++dblk) { \
      int xr = ((fr & 7) ^ ((dblk * 2 + (fr >> 3)) & 7)) << 4; \
      const unsigned char* vp = vbuf + (dblk * 16 + fr) * 128; \
      bf16x8 b0 = *(const bf16x8*)(vp + ((fg * 16) ^ xr)); \
      bf16x8 b1 = *(const bf16x8*)(vp + ((64 + fg * 16) ^ xr)); \
      acc[dblk] = __builtin_amdgcn_mfma_f32_16x16x32_bf16(pa0, b0, acc[dblk], 0, 0, 0); \
      acc[dblk] = __builtin_amdgcn_mfma_f32_16x16x32_bf16(pa1, b1, acc[dblk], 0, 0, 0); \
    } \
    __builtin_amdgcn_s_setprio(0); \
    if (hn_) STAGE_V_WRITE(nva, nvb, &VtRaw[(par_) ^ 1][0]); \
  } while (0)

  int par = 0;
  for (int kt = 0; kt < ntk; ++kt) {
    bool hn = (kt + 1 < ntk);
    UNIT(kt, par, hn, (kt + 1) * 64);
    par ^= 1;
  }

  // epilogue
#pragma unroll
  for (int r = 0; r < 4; ++r) {
    float l = l_part[r];
    l += __shfl_xor(l, 1); l += __shfl_xor(l, 2);
    l += __shfl_xor(l, 4); l += __shfl_xor(l, 8);
    float rl = __builtin_amdgcn_rcpf(l);
    int row = qt * 64 + wid * 16 + fg * 4 + r;
    unsigned short* orow = O + ((size_t)b * T_SEQ + row) * D_MODEL + h * HD;
#pragma unroll
    for (int d = 0; d < 4; ++d) orow[d * 16 + fr] = f2bf(acc[d][r] * rl);
  }
#undef UNIT
#undef STAGE_K
#undef STAGE_V_WRITE
}

// ---------------- launch ----------------
extern "C" void kernel_launch(void* const* d_in, const int* in_sizes, int n_in,
                              void* d_out, int out_size, void* d_ws, size_t ws_size,
                              hipStream_t stream) {
  const float* x   = (const float*)d_in[0];
  const int*   pos = (const int*)d_in[1];
  const float* Wq  = (const float*)d_in[2];
  const float* Wk  = (const float*)d_in[3];
  const float* Wv  = (const float*)d_in[4];
  const float* Wo  = (const float*)d_in[5];

  const size_t M  = (size_t)BATCH * T_SEQ;   // 4096
  const size_t DD = (size_t)D_MODEL * D_MODEL;

  char* ws = (char*)d_ws;
  unsigned short* xb  = (unsigned short*)ws; ws += M * D_MODEL * 2;
  unsigned short* Wqb = (unsigned short*)ws; ws += DD * 2;
  unsigned short* Wkb = (unsigned short*)ws; ws += DD * 2;
  unsigned short* Wvb = (unsigned short*)ws; ws += DD * 2;
  unsigned short* Wob = (unsigned short*)ws; ws += DD * 2;
  unsigned short* Qp  = (unsigned short*)ws; ws += M * D_MODEL * 2;
  unsigned short* Kp  = (unsigned short*)ws; ws += M * D_MODEL * 2;
  unsigned short* Vp  = (unsigned short*)ws; ws += M * D_MODEL * 2;
  unsigned short* Ob  = (unsigned short*)ws; ws += M * D_MODEL * 2;

  // merged casts: x + 4 weights, one dispatch (2^21 float4s)
  cast5_kernel<<<8192, 256, 0, stream>>>(x, Wq, Wk, Wv, Wo, xb, Wqb, Wkb, Wvb, Wob);

  // fused QKV projection with RoPE in epilogue (BM=128, BN=128, BK=64)
  gemm_bt<128, false, true><<<dim3(24, (unsigned)(M / 128)), 256, 0, stream>>>(
      xb, Wqb, Wkb, Wvb, Qp, Kp, Vp, pos, (int)M, D_MODEL);

  // attention: unpaired 1024 blocks, balanced quadruples (big first), XCD-grouped
  attn_kernel<<<dim3(1024), 256, 0, stream>>>(Qp, Kp, Vp, Ob);

  // output projection (fp32 out): BM=128, BN=64
  gemm_bt<64, true, false><<<dim3(16, (unsigned)(M / 128)), 256, 0, stream>>>(
      Ob, Wob, Wob, Wob, d_out, d_out, d_out, nullptr, (int)M, D_MODEL);
}